// Round 7
// baseline (93.351 us; speedup 1.0000x reference)
//
#include <hip/hip_runtime.h>
#include <hip/hip_bf16.h>
#include <cstdint>
#include <cstddef>

#define N_ROWS 8192
#define DIM_IN 512
#define MOT 64
#define INV_N2 (1.0f / (8192.0f * 8192.0f))
#define PAIR_BLOCKS 1536   // 6 blocks/CU exactly; 576*6 + 960*5 = 8256 tiles

typedef __attribute__((ext_vector_type(8))) short bf16x8;
typedef __attribute__((ext_vector_type(4))) float f32x4;

#define HALF_L2E 0.721347520444481703f   // 0.5 * log2(e)

__device__ inline unsigned short f2bf(float f) {
    union { __hip_bfloat16 h; unsigned short u; } cv;
    cv.h = __float2bfloat16(f);   // RNE
    return cv.u;
}
__device__ inline float bfbits2f(unsigned short u) {
    union { unsigned int i; float f; } cv;
    cv.i = ((unsigned int)u) << 16;
    return cv.f;
}
__device__ inline void gl_lds16(const void* g, void* l) {
    __builtin_amdgcn_global_load_lds(
        (const __attribute__((address_space(1))) unsigned int*)g,
        (__attribute__((address_space(3))) unsigned int*)l, 16, 0, 0);
}

// ---------------------------------------------------------------------------
// Phase 1 (fused A+B): functor2 (known good). Norms now stored PRE-SCALED:
// norms[row] = 0.5*log2e*||bf16(M_row)||^2.
// ---------------------------------------------------------------------------
__global__ __launch_bounds__(256) void functor2_kernel(
    const float* __restrict__ XA, const float* __restrict__ WA1, const float* __restrict__ bA1,
    const float* __restrict__ WA2, const float* __restrict__ bA2,
    const float* __restrict__ XB, const float* __restrict__ WB1, const float* __restrict__ bB1,
    const float* __restrict__ WB2, const float* __restrict__ bB2,
    float* __restrict__ MA, float* __restrict__ MB,
    float* __restrict__ nAo, float* __restrict__ nBo,
    unsigned short* __restrict__ PbfA, unsigned short* __restrict__ PbfB)
{
    const int half = blockIdx.x >> 8;          // 0: A path, 1: B path
    const float* X  = half ? XB  : XA;
    const float* W1 = half ? WB1 : WA1;
    const float* b1 = half ? bB1 : bA1;
    const float* W2 = half ? WB2 : WA2;
    const float* b2 = half ? bB2 : bA2;
    float* Mout  = half ? MB  : MA;
    float* norms = half ? nBo : nAo;
    unsigned short* Pbf = half ? PbfB : PbfA;

    __shared__ float XsT[64][34];
    __shared__ float Ws[64][64];
    __shared__ float HsT[64][34];

    const int t  = threadIdx.x;
    const int tx = t & 15;
    const int ty = t >> 4;
    const int row0 = (blockIdx.x & 255) * 32;

    float c[2][4] = {};

    for (int kc = 0; kc < DIM_IN; kc += 64) {
        #pragma unroll
        for (int q = 0; q < 2; ++q) {
            int idx = q * 256 + t;
            int row = idx >> 4;
            int k4  = (idx & 15) << 2;
            float4 v = *(const float4*)&X[(size_t)(row0 + row) * DIM_IN + kc + k4];
            XsT[k4 + 0][row] = v.x;
            XsT[k4 + 1][row] = v.y;
            XsT[k4 + 2][row] = v.z;
            XsT[k4 + 3][row] = v.w;
        }
        #pragma unroll
        for (int q = 0; q < 4; ++q) {
            int idx = q * 256 + t;
            int row = idx >> 4;
            int k4  = (idx & 15) << 2;
            *(float4*)&Ws[row][k4] = *(const float4*)&W1[(size_t)(kc + row) * MOT + k4];
        }
        __syncthreads();
        #pragma unroll 8
        for (int k = 0; k < 64; ++k) {
            float2 a = *(const float2*)&XsT[k][ty * 2];
            float4 b = *(const float4*)&Ws[k][tx * 4];
            float av[2] = {a.x, a.y};
            float bv[4] = {b.x, b.y, b.z, b.w};
            #pragma unroll
            for (int i = 0; i < 2; ++i)
                #pragma unroll
                for (int j = 0; j < 4; ++j)
                    c[i][j] = fmaf(av[i], bv[j], c[i][j]);
        }
        __syncthreads();
    }

    {
        float bias1[4];
        #pragma unroll
        for (int j = 0; j < 4; ++j) bias1[j] = b1[tx * 4 + j];
        #pragma unroll
        for (int i = 0; i < 2; ++i)
            #pragma unroll
            for (int j = 0; j < 4; ++j) {
                float h = c[i][j] + bias1[j];
                HsT[tx * 4 + j][ty * 2 + i] = fmaxf(h, 0.0f);
                c[i][j] = 0.0f;
            }
    }

    #pragma unroll
    for (int q = 0; q < 4; ++q) {
        int idx = q * 256 + t;
        int row = idx >> 4;
        int k4  = (idx & 15) << 2;
        *(float4*)&Ws[row][k4] = *(const float4*)&W2[(size_t)row * MOT + k4];
    }
    __syncthreads();

    #pragma unroll 8
    for (int k = 0; k < 64; ++k) {
        float2 a = *(const float2*)&HsT[k][ty * 2];
        float4 b = *(const float4*)&Ws[k][tx * 4];
        float av[2] = {a.x, a.y};
        float bv[4] = {b.x, b.y, b.z, b.w};
        #pragma unroll
        for (int i = 0; i < 2; ++i)
            #pragma unroll
            for (int j = 0; j < 4; ++j)
                c[i][j] = fmaf(av[i], bv[j], c[i][j]);
    }

    float bias2[4];
    #pragma unroll
    for (int j = 0; j < 4; ++j) bias2[j] = b2[tx * 4 + j];

    float p[2] = {0.0f, 0.0f};
    #pragma unroll
    for (int i = 0; i < 2; ++i) {
        unsigned short q4[4];
        int grow = row0 + ty * 2 + i;
        #pragma unroll
        for (int j = 0; j < 4; ++j) {
            float m = c[i][j] + bias2[j];
            Mout[(size_t)grow * MOT + tx * 4 + j] = m;
            q4[j] = f2bf(m);
            float mn = bfbits2f(q4[j]);
            p[i] = fmaf(mn, mn, p[i]);
        }
        int r = grow & 127;
        size_t tile = (size_t)(grow >> 7);
        int swz = (tx * 8) ^ ((r & 7) << 4);
        ushort4 v; v.x = q4[0]; v.y = q4[1]; v.z = q4[2]; v.w = q4[3];
        *(ushort4*)((char*)Pbf + tile * 16384 + (size_t)r * 128 + swz) = v;
    }
    #pragma unroll
    for (int off = 1; off < 16; off <<= 1)
        #pragma unroll
        for (int i = 0; i < 2; ++i)
            p[i] += __shfl_xor(p[i], off, 64);
    if (tx == 0) {
        norms[row0 + ty * 2 + 0] = HALF_L2E * p[0];   // pre-scaled
        norms[row0 + ty * 2 + 1] = HALF_L2E * p[1];
    }
}

// ---------------------------------------------------------------------------
__device__ inline void decode_tile(int id, int T, int TRI, int& which, int& bi, int& bj) {
    if (id < 2 * TRI) {
        which = (id < TRI) ? 0 : 1;
        if (which) id -= TRI;
        int r = (int)((sqrtf(8.0f * (float)id + 1.0f) - 1.0f) * 0.5f);
        while ((r + 1) * (r + 2) / 2 <= id) ++r;
        while (r * (r + 1) / 2 > id) --r;
        bi = r;
        bj = id - r * (r + 1) / 2;
    } else {
        id -= 2 * TRI;
        which = 2;
        bi = id >> 6;
        bj = id & (T - 1);
    }
}

__device__ inline void step_tile(int& which, int& bi, int& bj, int T) {
    ++bj;
    if (which == 2) {
        if (bj == T) { bj = 0; ++bi; }
    } else {
        if (bj > bi) { bj = 0; ++bi; if (bi == T) { bi = 0; ++which; } }
    }
}

// ---------------------------------------------------------------------------
// Phase 2 v5: identical body to v4, but grid 1536 (6 blocks/CU -- VGPR 84
// permits 6 waves/SIMD; round-6's 768 grid self-capped occupancy at 3).
// Norms arrive pre-scaled by 0.5*log2e; negation folded into fma modifier.
// ---------------------------------------------------------------------------
__global__ __launch_bounds__(256, 3) void pair_v5_kernel(
    const unsigned short* __restrict__ PA, const unsigned short* __restrict__ PB,
    const float* __restrict__ nA, const float* __restrict__ nB,
    float* __restrict__ out0)
{
    const int T   = N_ROWS / 128;      // 64
    const int TRI = T * (T + 1) / 2;   // 2080
    const float L2E = 1.44269504088896341f;

    __shared__ float red[4];

    const int t    = threadIdx.x;
    const int lane = t & 63;
    const int wave = t >> 6;
    const int wr   = wave >> 1, wc = wave & 1;
    const int sw   = (lane & 7) << 4;
    const int kb   = (lane >> 4) << 4;

    const int b     = blockIdx.x;
    const int start = (b < 576) ? b * 6 : 576 * 6 + (b - 576) * 5;
    const int len   = (b < 576) ? 6 : 5;

    bf16x8 af[4][2];
    float  nAr[4][4];    // pre-scaled A norms (positive; negated at use)

    auto loadA = [&](int w_, int bi_) {
        const unsigned short* P = (w_ == 1) ? PB : PA;
        const float* nP         = (w_ == 1) ? nB : nA;
        const char* base = (const char*)P + (size_t)bi_ * 16384;
        #pragma unroll
        for (int i = 0; i < 4; ++i) {
            const char* rowp = base + (size_t)(wr * 64 + i * 16 + (lane & 15)) * 128;
            #pragma unroll
            for (int k0 = 0; k0 < 2; ++k0)
                af[i][k0] = *(const bf16x8*)(rowp + ((k0 * 64 + kb) ^ sw));
            float4 n4 = *(const float4*)&nP[bi_ * 128 + wr * 64 + i * 16 + ((lane >> 4) << 2)];
            nAr[i][0] = n4.x; nAr[i][1] = n4.y; nAr[i][2] = n4.z; nAr[i][3] = n4.w;
        }
    };

    int cw, cbi, cbj;
    decode_tile(start, T, TRI, cw, cbi, cbj);
    loadA(cw, cbi);

    float s_acc = 0.0f;

    for (int u = 0; u < len; ++u) {
        const unsigned short* Q = (cw == 0) ? PA : PB;
        const float* nQ         = (cw == 0) ? nA : nB;
        const char* bbase = (const char*)Q + (size_t)cbj * 16384;

        f32x4 acc[4][4] = {};
        #pragma unroll
        for (int k0 = 0; k0 < 2; ++k0) {
            const int koff = (k0 * 64 + kb) ^ sw;
            bf16x8 bfr[4];
            #pragma unroll
            for (int j = 0; j < 4; ++j)
                bfr[j] = *(const bf16x8*)(bbase + (size_t)(wc * 64 + j * 16 + (lane & 15)) * 128 + koff);
            #pragma unroll
            for (int i = 0; i < 4; ++i)
                #pragma unroll
                for (int j = 0; j < 4; ++j)
                    acc[i][j] = __builtin_amdgcn_mfma_f32_16x16x32_bf16(af[i][k0], bfr[j], acc[i][j], 0, 0, 0);
        }

        float posB[4];
        #pragma unroll
        for (int j = 0; j < 4; ++j)
            posB[j] = nQ[cbj * 128 + wc * 64 + j * 16 + (lane & 15)];

        float sa[4] = {0.0f, 0.0f, 0.0f, 0.0f};
        if (cw != 2 && cbi == cbj) {              // diagonal tile: clamp to d>=0
            #pragma unroll
            for (int i = 0; i < 4; ++i)
                #pragma unroll
                for (int j = 0; j < 4; ++j)
                    #pragma unroll
                    for (int r = 0; r < 4; ++r) {
                        float tv = fmaf(acc[i][j][r], L2E, -nAr[i][r]) - posB[j];
                        sa[j] += exp2f(fminf(tv, 0.0f));
                    }
        } else {
            #pragma unroll
            for (int i = 0; i < 4; ++i)
                #pragma unroll
                for (int j = 0; j < 4; ++j)
                    #pragma unroll
                    for (int r = 0; r < 4; ++r) {
                        float tv = fmaf(acc[i][j][r], L2E, -nAr[i][r]) - posB[j];
                        sa[j] += exp2f(tv);
                    }
        }
        float stile = (sa[0] + sa[1]) + (sa[2] + sa[3]);

        float scale = (cw == 2) ? (-2.0f * INV_N2)
                                : ((cbi != cbj) ? (2.0f * INV_N2) : INV_N2);
        s_acc = fmaf(scale, stile, s_acc);

        if (u + 1 < len) {
            int nw = cw, nbi = cbi, nbj = cbj;
            step_tile(nw, nbi, nbj, T);
            if (nw != cw || nbi != cbi) loadA(nw, nbi);
            cw = nw; cbi = nbi; cbj = nbj;
        }
    }

    #pragma unroll
    for (int off = 32; off > 0; off >>= 1) s_acc += __shfl_xor(s_acc, off, 64);
    if (lane == 0) red[wave] = s_acc;
    __syncthreads();
    if (t == 0) atomicAdd(out0, red[0] + red[1] + red[2] + red[3]);
}

// ---------------------------------------------------------------------------
extern "C" void kernel_launch(void* const* d_in, const int* in_sizes, int n_in,
                              void* d_out, int out_size, void* d_ws, size_t ws_size,
                              hipStream_t stream)
{
    const float* XA  = (const float*)d_in[0];
    const float* XB  = (const float*)d_in[1];
    const float* WA1 = (const float*)d_in[2];
    const float* bA1 = (const float*)d_in[3];
    const float* WA2 = (const float*)d_in[4];
    const float* bA2 = (const float*)d_in[5];
    const float* WB1 = (const float*)d_in[6];
    const float* bB1 = (const float*)d_in[7];
    const float* WB2 = (const float*)d_in[8];
    const float* bB2 = (const float*)d_in[9];

    float* out = (float*)d_out;
    float* MA  = out + 1;
    float* MB  = out + 1 + (size_t)N_ROWS * MOT;
    float* nA  = (float*)d_ws;                           // 8192 f32 (pre-scaled)
    float* nB  = nA + N_ROWS;                            // 8192 f32 (pre-scaled)
    unsigned short* PA = (unsigned short*)(nB + N_ROWS); // 8192x64 bf16 (swizzled)
    unsigned short* PB = PA + (size_t)N_ROWS * MOT;

    hipMemsetAsync(d_out, 0, sizeof(float), stream);     // zero mmd accumulator

    functor2_kernel<<<512, 256, 0, stream>>>(XA, WA1, bA1, WA2, bA2,
                                             XB, WB1, bB1, WB2, bB2,
                                             MA, MB, nA, nB, PA, PB);

    pair_v5_kernel<<<PAIR_BLOCKS, 256, 0, stream>>>(PA, PB, nA, nB, out);
}

// Round 9
// 71.489 us; speedup vs baseline: 1.3058x; 1.3058x over previous
//
#include <hip/hip_runtime.h>
#include <hip/hip_bf16.h>
#include <cstdint>
#include <cstddef>

#define N_ROWS 8192
#define DIM_IN 512
#define MOT 64
#define INV_N2 (1.0f / (8192.0f * 8192.0f))
#define PAIR_BLOCKS 1024   // 4 blocks/CU exactly; 64*9 + 960*8 = 8256 tiles

typedef __attribute__((ext_vector_type(8))) short bf16x8;
typedef __attribute__((ext_vector_type(4))) float f32x4;

#define HALF_L2E 0.721347520444481703f   // 0.5 * log2(e)

__device__ inline float fast_exp2(float x) {
    return __builtin_amdgcn_exp2f(x);    // v_exp_f32, single TRANS inst
}

__device__ inline unsigned short f2bf(float f) {
    union { __hip_bfloat16 h; unsigned short u; } cv;
    cv.h = __float2bfloat16(f);   // RNE
    return cv.u;
}
__device__ inline float bfbits2f(unsigned short u) {
    union { unsigned int i; float f; } cv;
    cv.i = ((unsigned int)u) << 16;
    return cv.f;
}

// ---------------------------------------------------------------------------
// Phase 1 (fused A+B): functor2 (known good). norms = 0.5*log2e*||bf16(M)||^2.
// ---------------------------------------------------------------------------
__global__ __launch_bounds__(256) void functor2_kernel(
    const float* __restrict__ XA, const float* __restrict__ WA1, const float* __restrict__ bA1,
    const float* __restrict__ WA2, const float* __restrict__ bA2,
    const float* __restrict__ XB, const float* __restrict__ WB1, const float* __restrict__ bB1,
    const float* __restrict__ WB2, const float* __restrict__ bB2,
    float* __restrict__ MA, float* __restrict__ MB,
    float* __restrict__ nAo, float* __restrict__ nBo,
    unsigned short* __restrict__ PbfA, unsigned short* __restrict__ PbfB)
{
    const int half = blockIdx.x >> 8;          // 0: A path, 1: B path
    const float* X  = half ? XB  : XA;
    const float* W1 = half ? WB1 : WA1;
    const float* b1 = half ? bB1 : bA1;
    const float* W2 = half ? WB2 : WA2;
    const float* b2 = half ? bB2 : bA2;
    float* Mout  = half ? MB  : MA;
    float* norms = half ? nBo : nAo;
    unsigned short* Pbf = half ? PbfB : PbfA;

    __shared__ float XsT[64][34];
    __shared__ float Ws[64][64];
    __shared__ float HsT[64][34];

    const int t  = threadIdx.x;
    const int tx = t & 15;
    const int ty = t >> 4;
    const int row0 = (blockIdx.x & 255) * 32;

    float c[2][4] = {};

    for (int kc = 0; kc < DIM_IN; kc += 64) {
        #pragma unroll
        for (int q = 0; q < 2; ++q) {
            int idx = q * 256 + t;
            int row = idx >> 4;
            int k4  = (idx & 15) << 2;
            float4 v = *(const float4*)&X[(size_t)(row0 + row) * DIM_IN + kc + k4];
            XsT[k4 + 0][row] = v.x;
            XsT[k4 + 1][row] = v.y;
            XsT[k4 + 2][row] = v.z;
            XsT[k4 + 3][row] = v.w;
        }
        #pragma unroll
        for (int q = 0; q < 4; ++q) {
            int idx = q * 256 + t;
            int row = idx >> 4;
            int k4  = (idx & 15) << 2;
            *(float4*)&Ws[row][k4] = *(const float4*)&W1[(size_t)(kc + row) * MOT + k4];
        }
        __syncthreads();
        #pragma unroll 8
        for (int k = 0; k < 64; ++k) {
            float2 a = *(const float2*)&XsT[k][ty * 2];
            float4 b = *(const float4*)&Ws[k][tx * 4];
            float av[2] = {a.x, a.y};
            float bv[4] = {b.x, b.y, b.z, b.w};
            #pragma unroll
            for (int i = 0; i < 2; ++i)
                #pragma unroll
                for (int j = 0; j < 4; ++j)
                    c[i][j] = fmaf(av[i], bv[j], c[i][j]);
        }
        __syncthreads();
    }

    {
        float bias1[4];
        #pragma unroll
        for (int j = 0; j < 4; ++j) bias1[j] = b1[tx * 4 + j];
        #pragma unroll
        for (int i = 0; i < 2; ++i)
            #pragma unroll
            for (int j = 0; j < 4; ++j) {
                float h = c[i][j] + bias1[j];
                HsT[tx * 4 + j][ty * 2 + i] = fmaxf(h, 0.0f);
                c[i][j] = 0.0f;
            }
    }

    #pragma unroll
    for (int q = 0; q < 4; ++q) {
        int idx = q * 256 + t;
        int row = idx >> 4;
        int k4  = (idx & 15) << 2;
        *(float4*)&Ws[row][k4] = *(const float4*)&W2[(size_t)row * MOT + k4];
    }
    __syncthreads();

    #pragma unroll 8
    for (int k = 0; k < 64; ++k) {
        float2 a = *(const float2*)&HsT[k][ty * 2];
        float4 b = *(const float4*)&Ws[k][tx * 4];
        float av[2] = {a.x, a.y};
        float bv[4] = {b.x, b.y, b.z, b.w};
        #pragma unroll
        for (int i = 0; i < 2; ++i)
            #pragma unroll
            for (int j = 0; j < 4; ++j)
                c[i][j] = fmaf(av[i], bv[j], c[i][j]);
    }

    float bias2[4];
    #pragma unroll
    for (int j = 0; j < 4; ++j) bias2[j] = b2[tx * 4 + j];

    float p[2] = {0.0f, 0.0f};
    #pragma unroll
    for (int i = 0; i < 2; ++i) {
        unsigned short q4[4];
        int grow = row0 + ty * 2 + i;
        #pragma unroll
        for (int j = 0; j < 4; ++j) {
            float m = c[i][j] + bias2[j];
            Mout[(size_t)grow * MOT + tx * 4 + j] = m;
            q4[j] = f2bf(m);
            float mn = bfbits2f(q4[j]);
            p[i] = fmaf(mn, mn, p[i]);
        }
        int r = grow & 127;
        size_t tile = (size_t)(grow >> 7);
        int swz = (tx * 8) ^ ((r & 7) << 4);
        ushort4 v; v.x = q4[0]; v.y = q4[1]; v.z = q4[2]; v.w = q4[3];
        *(ushort4*)((char*)Pbf + tile * 16384 + (size_t)r * 128 + swz) = v;
    }
    #pragma unroll
    for (int off = 1; off < 16; off <<= 1)
        #pragma unroll
        for (int i = 0; i < 2; ++i)
            p[i] += __shfl_xor(p[i], off, 64);
    if (tx == 0) {
        norms[row0 + ty * 2 + 0] = HALF_L2E * p[0];   // pre-scaled
        norms[row0 + ty * 2 + 1] = HALF_L2E * p[1];
    }
}

// ---------------------------------------------------------------------------
__device__ inline void decode_tile(int id, int T, int TRI, int& which, int& bi, int& bj) {
    if (id < 2 * TRI) {
        which = (id < TRI) ? 0 : 1;
        if (which) id -= TRI;
        int r = (int)((sqrtf(8.0f * (float)id + 1.0f) - 1.0f) * 0.5f);
        while ((r + 1) * (r + 2) / 2 <= id) ++r;
        while (r * (r + 1) / 2 > id) --r;
        bi = r;
        bj = id - r * (r + 1) / 2;
    } else {
        id -= 2 * TRI;
        which = 2;
        bi = id >> 6;
        bj = id & (T - 1);
    }
}

__device__ inline void step_tile(int& which, int& bi, int& bj, int T) {
    ++bj;
    if (which == 2) {
        if (bj == T) { bj = 0; ++bi; }
    } else {
        if (bj > bi) { bj = 0; ++bi; if (bi == T) { bi = 0; ++which; } }
    }
}

// ---------------------------------------------------------------------------
// Phase 2 v6: LDS-free, barrier-free. Per-wave 64x64 tile computed as TWO
// 64x32 passes (acc[4][2] = 32 AGPRs) so arch+acc regs fit <=128 -> 4
// waves/SIMD (R6/R7 were stuck at 2: 84 arch + 64 acc = 148 > 128).
// __builtin_amdgcn_exp2f = native v_exp_f32 (libm exp2f was an ocml call).
// ---------------------------------------------------------------------------
__global__ __launch_bounds__(256, 4) void pair_v6_kernel(
    const unsigned short* __restrict__ PA, const unsigned short* __restrict__ PB,
    const float* __restrict__ nA, const float* __restrict__ nB,
    float* __restrict__ out0)
{
    const int T   = N_ROWS / 128;      // 64
    const int TRI = T * (T + 1) / 2;   // 2080
    const float L2E = 1.44269504088896341f;

    __shared__ float red[4];

    const int t    = threadIdx.x;
    const int lane = t & 63;
    const int wave = t >> 6;
    const int wr   = wave >> 1, wc = wave & 1;
    const int sw   = (lane & 7) << 4;
    const int kb   = (lane >> 4) << 4;

    const int b     = blockIdx.x;
    const int start = (b < 64) ? b * 9 : b * 8 + 64;
    const int len   = (b < 64) ? 9 : 8;

    bf16x8 af[4][2];
    float  nAr[4][4];    // pre-scaled (0.5*log2e) A norms

    auto loadA = [&](int w_, int bi_) {
        const unsigned short* P = (w_ == 1) ? PB : PA;
        const float* nP         = (w_ == 1) ? nB : nA;
        const char* base = (const char*)P + (size_t)bi_ * 16384;
        #pragma unroll
        for (int i = 0; i < 4; ++i) {
            const char* rowp = base + (size_t)(wr * 64 + i * 16 + (lane & 15)) * 128;
            #pragma unroll
            for (int k0 = 0; k0 < 2; ++k0)
                af[i][k0] = *(const bf16x8*)(rowp + ((k0 * 64 + kb) ^ sw));
            float4 n4 = *(const float4*)&nP[bi_ * 128 + wr * 64 + i * 16 + ((lane >> 4) << 2)];
            nAr[i][0] = n4.x; nAr[i][1] = n4.y; nAr[i][2] = n4.z; nAr[i][3] = n4.w;
        }
    };

    int cw, cbi, cbj;
    decode_tile(start, T, TRI, cw, cbi, cbj);
    loadA(cw, cbi);

    float s_acc = 0.0f;

    for (int u = 0; u < len; ++u) {
        const unsigned short* Q = (cw == 0) ? PA : PB;
        const float* nQ         = (cw == 0) ? nA : nB;
        const char* bbase = (const char*)Q + (size_t)cbj * 16384;
        const bool diag = (cw != 2) && (cbi == cbj);

        float sa[4] = {0.0f, 0.0f, 0.0f, 0.0f};

        #pragma unroll
        for (int jh = 0; jh < 2; ++jh) {
            // ---- MFMA: A regs x B(L2), 64x32 output ----
            f32x4 acc[4][2] = {};
            #pragma unroll
            for (int k0 = 0; k0 < 2; ++k0) {
                const int koff = (k0 * 64 + kb) ^ sw;
                bf16x8 bfr[2];
                #pragma unroll
                for (int j = 0; j < 2; ++j)
                    bfr[j] = *(const bf16x8*)(bbase +
                        (size_t)(wc * 64 + jh * 32 + j * 16 + (lane & 15)) * 128 + koff);
                #pragma unroll
                for (int i = 0; i < 4; ++i)
                    #pragma unroll
                    for (int j = 0; j < 2; ++j)
                        acc[i][j] = __builtin_amdgcn_mfma_f32_16x16x32_bf16(af[i][k0], bfr[j], acc[i][j], 0, 0, 0);
            }

            float posB[2];
            #pragma unroll
            for (int j = 0; j < 2; ++j)
                posB[j] = nQ[cbj * 128 + wc * 64 + jh * 32 + j * 16 + (lane & 15)];

            // ---- epilogue: exp2(dot*log2e - nA' - nB') ----
            if (diag) {                           // clamp to d>=0 (exact diag)
                #pragma unroll
                for (int i = 0; i < 4; ++i)
                    #pragma unroll
                    for (int j = 0; j < 2; ++j)
                        #pragma unroll
                        for (int r = 0; r < 4; ++r) {
                            float tv = fmaf(acc[i][j][r], L2E, -nAr[i][r]) - posB[j];
                            sa[jh * 2 + j] += fast_exp2(fminf(tv, 0.0f));
                        }
            } else {
                #pragma unroll
                for (int i = 0; i < 4; ++i)
                    #pragma unroll
                    for (int j = 0; j < 2; ++j)
                        #pragma unroll
                        for (int r = 0; r < 4; ++r) {
                            float tv = fmaf(acc[i][j][r], L2E, -nAr[i][r]) - posB[j];
                            sa[jh * 2 + j] += fast_exp2(tv);
                        }
            }
        }

        float stile = (sa[0] + sa[1]) + (sa[2] + sa[3]);
        float scale = (cw == 2) ? (-2.0f * INV_N2)
                                : ((cbi != cbj) ? (2.0f * INV_N2) : INV_N2);
        s_acc = fmaf(scale, stile, s_acc);

        if (u + 1 < len) {
            int nw = cw, nbi = cbi, nbj = cbj;
            step_tile(nw, nbi, nbj, T);
            if (nw != cw || nbi != cbi) loadA(nw, nbi);
            cw = nw; cbi = nbi; cbj = nbj;
        }
    }

    #pragma unroll
    for (int off = 32; off > 0; off >>= 1) s_acc += __shfl_xor(s_acc, off, 64);
    if (lane == 0) red[wave] = s_acc;
    __syncthreads();
    if (t == 0) atomicAdd(out0, red[0] + red[1] + red[2] + red[3]);
}

// ---------------------------------------------------------------------------
extern "C" void kernel_launch(void* const* d_in, const int* in_sizes, int n_in,
                              void* d_out, int out_size, void* d_ws, size_t ws_size,
                              hipStream_t stream)
{
    const float* XA  = (const float*)d_in[0];
    const float* XB  = (const float*)d_in[1];
    const float* WA1 = (const float*)d_in[2];
    const float* bA1 = (const float*)d_in[3];
    const float* WA2 = (const float*)d_in[4];
    const float* bA2 = (const float*)d_in[5];
    const float* WB1 = (const float*)d_in[6];
    const float* bB1 = (const float*)d_in[7];
    const float* WB2 = (const float*)d_in[8];
    const float* bB2 = (const float*)d_in[9];

    float* out = (float*)d_out;
    float* MA  = out + 1;
    float* MB  = out + 1 + (size_t)N_ROWS * MOT;
    float* nA  = (float*)d_ws;                           // 8192 f32 (pre-scaled)
    float* nB  = nA + N_ROWS;                            // 8192 f32 (pre-scaled)
    unsigned short* PA = (unsigned short*)(nB + N_ROWS); // 8192x64 bf16 (swizzled)
    unsigned short* PB = PA + (size_t)N_ROWS * MOT;

    hipMemsetAsync(d_out, 0, sizeof(float), stream);     // zero mmd accumulator

    functor2_kernel<<<512, 256, 0, stream>>>(XA, WA1, bA1, WA2, bA2,
                                             XB, WB1, bB1, WB2, bB2,
                                             MA, MB, nA, nB, PA, PB);

    pair_v6_kernel<<<PAIR_BLOCKS, 256, 0, stream>>>(PA, PB, nA, nB, out);
}